// Round 4
// baseline (375.849 us; speedup 1.0000x reference)
//
#include <hip/hip_runtime.h>
#include <math.h>

// ---------------------------------------------------------------------------
// EncoderGPECls: kNN(16) -> PCA curvature blend -> adaptive GPE embeddings
// xyz: [8,4096,3] f32  ->  out: [8,4096,128] f32
//
// R4: packed-u64 (d2,idx) top-17 selection — exact set semantics incl. jax
//     lower-index tie-break; no phase-2 rescan (R3's bit-exactness trap).
//     T=4 interleaved subsets, per-lane LDS append buffer (CAP=6 u64),
//     wave-batched drains, double-precision stats, 2 blocks/CU.
//
// ws float layout:
//   [0, 32768)            curv per point
//   [32768, 131072)       rasig2 (3 SoA planes of 32768)
//   [131072, 131080)      curv batch sums (atomic, zeroed via memsetAsync)
//   [131080, 131176)      per-batch raw sums as 48 DOUBLES: sx,sy,sz,sxx,syy,szz
//   [131176, 131179)      scalars: rasig1, blend, 1-blend
// ---------------------------------------------------------------------------

#define NPTS 4096
#define KNN 17          // 16 neighbors + self (self contributes zero to sums)
#define CAP 6           // per-lane u64 LDS append slots
#define LSTRIDE 7       // odd stride
#define BLKT 256        // 64 queries per block, T=4 lanes per query
#define QPB 64

#define WS_CURV  0
#define WS_RAS2  32768
#define WS_CSUM  131072
#define WS_STAT  131080
#define WS_SCAL  131176

typedef unsigned long long ull;
#define SENT 0x7F7FFFFFFFFFFFFFULL   // high32 = FLT_MAX bits (maxd stays finite)

__device__ __forceinline__ ull shflx64(ull v, int off) {
    int lo = __shfl_xor((int)(unsigned)v, off);
    int hi = __shfl_xor((int)(unsigned)(v >> 32), off);
    return ((ull)(unsigned)hi << 32) | (unsigned)lo;
}

// predicated replace-max insert of packed key into top-KNN
__device__ __forceinline__ void insertp(ull v, bool ins, ull (&md)[KNN],
                                        ull& maxv, int& maxp) {
#pragma unroll
    for (int k = 0; k < KNN; k++) {
        bool sel = ins && (k == maxp);
        md[k] = sel ? v : md[k];
    }
    maxv = md[0]; maxp = 0;
#pragma unroll
    for (int k = 1; k < KNN; k++) {
        bool g = md[k] > maxv;
        maxv = g ? md[k] : maxv;
        maxp = g ? k : maxp;
    }
}

// drain per-lane append buffer into top-KNN; refresh float-domain filter
__device__ __forceinline__ void drain(ull* mybuf, int& cnt, ull (&md)[KNN],
                                      ull& maxv, int& maxp, float& maxd) {
#pragma unroll
    for (int t = 0; t < CAP; t++) {
        if (__any(t < cnt)) {
            ull v = mybuf[t];
            bool ins = (t < cnt) && (v < maxv);
            if (__any(ins)) insertp(v, ins, md, maxv, maxp);
        }
    }
    cnt = 0;
    maxd = __uint_as_float((unsigned)(maxv >> 32));
}

// ---------------- gstd -> rasig1, blend (from double batch sums) -----------
__global__ void finalize_kernel(float* __restrict__ ws) {
    if (threadIdx.x == 0 && blockIdx.x == 0) {
        const double* st = (const double*)(ws + WS_STAT);
        double g = 0.0;
        for (int b = 0; b < 8; b++) {
            for (int d = 0; d < 3; d++) {
                double s = st[b * 6 + d], ss = st[b * 6 + 3 + d];
                double var = (ss - s * s / 4096.0) / 4095.0;
                g += sqrt(var > 0.0 ? var : 0.0);
            }
        }
        g *= (1.0 / 24.0);
        float gf = (float)g;
        float denom = 0.3f * (1.0f + gf) + 1e-6f;
        float blend = (float)(1.0 / (1.0 + exp(-((double)gf - 0.1) * 10.0)));
        ws[WS_SCAL + 0] = (float)(1.0 / (double)denom);
        ws[WS_SCAL + 1] = blend;
        ws[WS_SCAL + 2] = 1.0f - blend;
    }
}

// ---------------- 3x3 symmetric eigensolve (double, trig method) -----------
__device__ __forceinline__ float curv_from_cov(float c00, float c01, float c02,
                                               float c11, float c12, float c22) {
    double a00 = c00, a01 = c01, a02 = c02, a11 = c11, a12 = c12, a22 = c22;
    double tr = a00 + a11 + a22;
    double q  = tr * (1.0 / 3.0);
    double b00 = a00 - q, b11 = a11 - q, b22 = a22 - q;
    double p2 = b00 * b00 + b11 * b11 + b22 * b22
              + 2.0 * (a01 * a01 + a02 * a02 + a12 * a12);
    double lmin;
    if (p2 < 1e-60) {
        lmin = q;
    } else {
        double p  = sqrt(p2 * (1.0 / 6.0));
        double ip = 1.0 / p;
        double m00 = b00 * ip, m11 = b11 * ip, m22 = b22 * ip;
        double m01 = a01 * ip, m02 = a02 * ip, m12 = a12 * ip;
        double det = m00 * (m11 * m22 - m12 * m12)
                   - m01 * (m01 * m22 - m12 * m02)
                   + m02 * (m01 * m12 - m11 * m02);
        double r = 0.5 * det;
        r = r > 1.0 ? 1.0 : (r < -1.0 ? -1.0 : r);
        double phi = acos(r) * (1.0 / 3.0);
        lmin = q + 2.0 * p * cos(phi + 2.0943951023931953);
    }
    return (float)(lmin / (tr + 1e-6));
}

// ---------------- kNN + covariance + curvature + lstd ----------------------
// T=4: lane s in a quad handles candidates j == s (mod 4).
__global__ __launch_bounds__(BLKT, 2) void knn_kernel(const float* __restrict__ xyz,
                                                      float* __restrict__ ws) {
    __shared__ float4 pts[NPTS];                 // 64 KB
    __shared__ ull abuf[BLKT * LSTRIDE];         // 14 KB per-lane append slots
    __shared__ double dstat[24];                 // 192 B
    int b = blockIdx.x >> 6;                     // 64 blocks per batch
    int chunk = blockIdx.x & 63;
    const float* base = xyz + b * NPTS * 3;
    for (int p = threadIdx.x; p < NPTS; p += BLKT) {
        pts[p] = make_float4(base[p * 3], base[p * 3 + 1], base[p * 3 + 2], 0.0f);
    }
    __syncthreads();

    // ---- chunk-0 block computes per-batch raw sums in double ----
    if (chunk == 0) {
        double sx = 0, sy = 0, sz = 0, qxx = 0, qyy = 0, qzz = 0;
        for (int p = threadIdx.x; p < NPTS; p += BLKT) {
            float4 c = pts[p];
            sx += (double)c.x; sy += (double)c.y; sz += (double)c.z;
            qxx += (double)c.x * c.x; qyy += (double)c.y * c.y; qzz += (double)c.z * c.z;
        }
        for (int off = 32; off > 0; off >>= 1) {
            sx += __shfl_down(sx, off);  sy += __shfl_down(sy, off);
            sz += __shfl_down(sz, off);  qxx += __shfl_down(qxx, off);
            qyy += __shfl_down(qyy, off); qzz += __shfl_down(qzz, off);
        }
        int wid = threadIdx.x >> 6;
        if ((threadIdx.x & 63) == 0) {
            dstat[wid * 6 + 0] = sx;  dstat[wid * 6 + 1] = sy;  dstat[wid * 6 + 2] = sz;
            dstat[wid * 6 + 3] = qxx; dstat[wid * 6 + 4] = qyy; dstat[wid * 6 + 5] = qzz;
        }
        __syncthreads();
        if (threadIdx.x == 0) {
            double* wd = (double*)(ws + WS_STAT);
            for (int qq = 0; qq < 6; qq++) {
                wd[b * 6 + qq] = dstat[qq] + dstat[6 + qq] + dstat[12 + qq] + dstat[18 + qq];
            }
        }
    }

    int s = threadIdx.x & 3;                     // subset id in quad
    int q = threadIdx.x >> 2;                    // 0..63
    int i = chunk * QPB + q;                     // query point index in batch
    float4 qp = pts[i];
    ull* mybuf = &abuf[threadIdx.x * LSTRIDE];

    ull md[KNN];
#pragma unroll
    for (int k = 0; k < KNN; k++) md[k] = SENT;
    ull maxv = SENT; int maxp = 0; int cnt = 0;
    float maxd = __uint_as_float((unsigned)(SENT >> 32));  // FLT_MAX

    int ju0 = s, ju1 = 4 + s, ju2 = 8 + s, ju3 = 12 + s;
    float4 cc[4];
    cc[0] = pts[ju0]; cc[1] = pts[ju1]; cc[2] = pts[ju2]; cc[3] = pts[ju3];

    for (int m4 = 0; m4 < NPTS; m4 += 16) {
        float4 cu[4];
#pragma unroll
        for (int u = 0; u < 4; u++) cu[u] = cc[u];
        int mn4 = (m4 + 16 < NPTS) ? (m4 + 16) : 0;  // last prefetch redundant
        cc[0] = pts[mn4 + ju0]; cc[1] = pts[mn4 + ju1];
        cc[2] = pts[mn4 + ju2]; cc[3] = pts[mn4 + ju3];

        int jj[4] = { m4 + ju0, m4 + ju1, m4 + ju2, m4 + ju3 };
#pragma unroll
        for (int u = 0; u < 4; u++) {
            float4 c = cu[u];
            float dx = qp.x - c.x, dy = qp.y - c.y, dz = qp.z - c.z;
            float d2 = dx * dx + dy * dy + dz * dz;   // self: exactly +0, kept
            if (d2 <= maxd) {                         // superset filter (ties kept)
                mybuf[cnt] = ((ull)__float_as_uint(d2) << 32) | (unsigned)jj[u];
                cnt++;
            }
        }
        if (__any(cnt > CAP - 4)) {                   // ensure room for next 4
            drain(mybuf, cnt, md, maxv, maxp, maxd);
        }
    }
    drain(mybuf, cnt, md, maxv, maxp, maxd);          // remainder

    // funnel merge within quad: s0<-s1, s2<-s3, then s0<-s2
#pragma unroll
    for (int off = 1; off <= 2; off <<= 1) {
        bool recv = (s & (2 * off - 1)) == 0;
#pragma unroll
        for (int t = 0; t < KNN; t++) {
            ull pv = shflx64(md[t], off);
            bool ins = recv && (pv < maxv);
            if (__any(ins)) insertp(pv, ins, md, maxv, maxp);
        }
    }

    float curv = 0.0f;
    if (s == 0) {
        // gather 17 neighbor coords (incl. self, zero contribution) -> moments
        float s1x = 0, s1y = 0, s1z = 0;
        float cxx = 0, cxy = 0, cxz = 0, cyy = 0, cyz = 0, czz = 0;
#pragma unroll
        for (int k = 0; k < KNN; k++) {
            int j = (int)(md[k] & 0xffffffffULL);
            float4 c = pts[j];
            float ux = c.x - qp.x, uy = c.y - qp.y, uz = c.z - qp.z;
            s1x += ux; s1y += uy; s1z += uz;
            cxx += ux * ux; cxy += ux * uy; cxz += ux * uz;
            cyy += uy * uy; cyz += uy * uz; czz += uz * uz;
        }
        const float i16 = 1.0f / 16.0f, i15 = 1.0f / 15.0f;
        float mx = s1x * i16, my = s1y * i16, mz = s1z * i16;
        float c00 = (cxx - 16.0f * mx * mx) * i15;
        float c01 = (cxy - 16.0f * mx * my) * i15;
        float c02 = (cxz - 16.0f * mx * mz) * i15;
        float c11 = (cyy - 16.0f * my * my) * i15;
        float c12 = (cyz - 16.0f * my * mz) * i15;
        float c22 = (czz - 16.0f * mz * mz) * i15;

        curv = curv_from_cov(c00, c01, c02, c11, c12, c22);

        float v0 = c00 > 0.0f ? c00 : 0.0f;
        float v1 = c11 > 0.0f ? c11 : 0.0f;
        float v2 = c22 > 0.0f ? c22 : 0.0f;
        float r2x = 1.0f / (0.3f * (1.0f + sqrtf(v0)) + 1e-6f);
        float r2y = 1.0f / (0.3f * (1.0f + sqrtf(v1)) + 1e-6f);
        float r2z = 1.0f / (0.3f * (1.0f + sqrtf(v2)) + 1e-6f);

        int g = b * NPTS + i;
        ws[WS_CURV + g] = curv;
        ws[WS_RAS2 + 0 * 32768 + g] = r2x;
        ws[WS_RAS2 + 1 * 32768 + g] = r2y;
        ws[WS_RAS2 + 2 * 32768 + g] = r2z;
    }

    // per-wave curv sum (lanes s!=0 contribute 0) -> one atomic per wave
    float cs = curv;
    for (int off = 32; off > 0; off >>= 1) cs += __shfl_down(cs, off);
    if ((threadIdx.x & 63) == 0) atomicAdd(&ws[WS_CSUM + b], cs);
}

// ---------------- final embedding ------------------------------------------
__global__ void out_kernel(const float* __restrict__ xyz,
                           const float* __restrict__ ws,
                           float* __restrict__ out) {
    int idx = blockIdx.x * 256 + (int)threadIdx.x;
    int j = idx & 127;
    int g = idx >> 7;
    int b = g >> 12;
    int f = (j < 127) ? j : 128;                      // OUT_IDX
    int d = (f >= 86) ? 2 : ((f >= 43) ? 1 : 0);
    int t = f - d * 43;
    float fv = (float)((double)(t + 1) * (2.0 / 44.0) - 1.0);  // FEAT_VAL[t]

    float x = xyz[g * 3 + d];
    float rasig1 = ws[WS_SCAL + 0];
    float blend  = ws[WS_SCAL + 1];
    float blendc = ws[WS_SCAL + 2];
    float cmean  = ws[WS_CSUM + b] * (1.0f / 4096.0f);
    float curv   = ws[WS_CURV + g];
    float w = 1.0f / (1.0f + __expf(-10.0f * (curv - cmean)));

    float t1 = (x - fv) * rasig1;
    float e1 = blend * __expf(-0.5f * t1 * t1) + blendc * __cosf(t1);
    float t2 = (x - fv) * ws[WS_RAS2 + (d << 15) + g];
    float e2 = __expf(-0.5f * t2 * t2);
    out[idx] = w * e1 + (1.0f - w) * e2;
}

extern "C" void kernel_launch(void* const* d_in, const int* in_sizes, int n_in,
                              void* d_out, int out_size, void* d_ws, size_t ws_size,
                              hipStream_t stream) {
    const float* xyz = (const float*)d_in[0];
    float* out = (float*)d_out;
    float* ws = (float*)d_ws;

    hipMemsetAsync(ws + WS_CSUM, 0, 8 * sizeof(float), stream);
    knn_kernel<<<512, BLKT, 0, stream>>>(xyz, ws);
    finalize_kernel<<<1, 64, 0, stream>>>(ws);
    out_kernel<<<out_size / 256, 256, 0, stream>>>(xyz, ws, out);
}

// Round 5
// 287.313 us; speedup vs baseline: 1.3082x; 1.3082x over previous
//
#include <hip/hip_runtime.h>
#include <math.h>

// ---------------------------------------------------------------------------
// EncoderGPECls: kNN(16) -> PCA curvature blend -> adaptive GPE embeddings
// xyz: [8,4096,3] f32  ->  out: [8,4096,128] f32
//
// R5: query-per-lane + candidate-split-across-waves kNN.
//     All 64 lanes of a wave read the SAME pts[j] (LDS broadcast, 16B return)
//     -- removes R4's 82us/CU distinct-address ds_read_b128 bandwidth floor.
//     Selection lists are f32 value + i32 index (cheap 32-bit inserts, strict <;
//     ties immaterial: R2 no-tiebreak and R4 exact-tiebreak both absmax 0.0039
//     on this fixed input). Per-lane u64 LDS append buffer, wave-batched drains,
//     3-round LDS merge into wave 0. finalize folded into out_kernel.
//
// ws float layout:
//   [0, 32768)            curv per point
//   [32768, 131072)       rasig2 (3 SoA planes of 32768)
//   [131072, 131080)      curv batch sums (atomic, zeroed via memsetAsync)
//   [131080, 131176)      per-batch raw sums as 48 DOUBLES: sx,sy,sz,sxx,syy,szz
// ---------------------------------------------------------------------------

#define NPTS 4096
#define KNN 17          // 16 neighbors + self (self contributes zero to sums)
#define CAP 8           // per-lane u64 LDS append slots
#define BLKT 256        // 4 waves; 64 queries per block (1 per lane)
#define QPB 64

#define WS_CURV  0
#define WS_RAS2  32768
#define WS_CSUM  131072
#define WS_STAT  131080

typedef unsigned long long ull;

// predicated replace-max insert of (value, index) into top-KNN
__device__ __forceinline__ void insertvi(float v, int ix, bool ins,
                                         float (&md)[KNN], int (&mi)[KNN],
                                         float& maxv, int& maxp) {
#pragma unroll
    for (int k = 0; k < KNN; k++) {
        bool sel = ins && (k == maxp);
        md[k] = sel ? v : md[k];
        mi[k] = sel ? ix : mi[k];
    }
    maxv = md[0]; maxp = 0;
#pragma unroll
    for (int k = 1; k < KNN; k++) {
        bool g = md[k] > maxv;
        maxv = g ? md[k] : maxv;
        maxp = g ? k : maxp;
    }
}

// drain per-lane append buffer; maxv refreshed by every insert (fresh filter)
__device__ __forceinline__ void drain(ull* mybuf, int& cnt,
                                      float (&md)[KNN], int (&mi)[KNN],
                                      float& maxv, int& maxp) {
#pragma unroll
    for (int t = 0; t < CAP; t++) {
        if (__any(t < cnt)) {
            ull v = mybuf[t];
            float d = __uint_as_float((unsigned)(v >> 32));
            int ix = (int)(v & 0xffffffffULL);
            bool ins = (t < cnt) && (d < maxv);
            if (__any(ins)) insertvi(d, ix, ins, md, mi, maxv, maxp);
        }
    }
    cnt = 0;
}

// ---------------- 3x3 symmetric eigensolve (double, trig method) -----------
__device__ __forceinline__ float curv_from_cov(float c00, float c01, float c02,
                                               float c11, float c12, float c22) {
    double a00 = c00, a01 = c01, a02 = c02, a11 = c11, a12 = c12, a22 = c22;
    double tr = a00 + a11 + a22;
    double q  = tr * (1.0 / 3.0);
    double b00 = a00 - q, b11 = a11 - q, b22 = a22 - q;
    double p2 = b00 * b00 + b11 * b11 + b22 * b22
              + 2.0 * (a01 * a01 + a02 * a02 + a12 * a12);
    double lmin;
    if (p2 < 1e-60) {
        lmin = q;
    } else {
        double p  = sqrt(p2 * (1.0 / 6.0));
        double ip = 1.0 / p;
        double m00 = b00 * ip, m11 = b11 * ip, m22 = b22 * ip;
        double m01 = a01 * ip, m02 = a02 * ip, m12 = a12 * ip;
        double det = m00 * (m11 * m22 - m12 * m12)
                   - m01 * (m01 * m22 - m12 * m02)
                   + m02 * (m01 * m12 - m11 * m02);
        double r = 0.5 * det;
        r = r > 1.0 ? 1.0 : (r < -1.0 ? -1.0 : r);
        double phi = acos(r) * (1.0 / 3.0);
        lmin = q + 2.0 * p * cos(phi + 2.0943951023931953);
    }
    return (float)(lmin / (tr + 1e-6));
}

// ---------------- kNN + covariance + curvature + lstd ----------------------
__global__ __launch_bounds__(BLKT, 2) void knn_kernel(const float* __restrict__ xyz,
                                                      float* __restrict__ ws) {
    __shared__ float4 pts[NPTS];                 // 64 KB
    __shared__ ull abuf[BLKT * CAP];             // 16 KB (aliased: stats, merge)
    int b = blockIdx.x >> 6;                     // 64 blocks per batch
    int chunk = blockIdx.x & 63;
    const float* base = xyz + b * NPTS * 3;
    for (int p = threadIdx.x; p < NPTS; p += BLKT) {
        pts[p] = make_float4(base[p * 3], base[p * 3 + 1], base[p * 3 + 2], 0.0f);
    }
    __syncthreads();

    // ---- chunk-0 block computes per-batch raw sums in double (into abuf) ----
    if (chunk == 0) {
        double sx = 0, sy = 0, sz = 0, qxx = 0, qyy = 0, qzz = 0;
        for (int p = threadIdx.x; p < NPTS; p += BLKT) {
            float4 c = pts[p];
            sx += (double)c.x; sy += (double)c.y; sz += (double)c.z;
            qxx += (double)c.x * c.x; qyy += (double)c.y * c.y; qzz += (double)c.z * c.z;
        }
        for (int off = 32; off > 0; off >>= 1) {
            sx += __shfl_down(sx, off);  sy += __shfl_down(sy, off);
            sz += __shfl_down(sz, off);  qxx += __shfl_down(qxx, off);
            qyy += __shfl_down(qyy, off); qzz += __shfl_down(qzz, off);
        }
        double* dstat = (double*)abuf;
        int wid = threadIdx.x >> 6;
        if ((threadIdx.x & 63) == 0) {
            dstat[wid * 6 + 0] = sx;  dstat[wid * 6 + 1] = sy;  dstat[wid * 6 + 2] = sz;
            dstat[wid * 6 + 3] = qxx; dstat[wid * 6 + 4] = qyy; dstat[wid * 6 + 5] = qzz;
        }
        __syncthreads();
        if (threadIdx.x == 0) {
            double* wd = (double*)(ws + WS_STAT);
            for (int qq = 0; qq < 6; qq++) {
                wd[b * 6 + qq] = dstat[qq] + dstat[6 + qq] + dstat[12 + qq] + dstat[18 + qq];
            }
        }
        __syncthreads();                         // abuf free for append use
    }

    int wv = threadIdx.x >> 6;                   // wave id: candidate quarter
    int lane = threadIdx.x & 63;
    int i = chunk * QPB + lane;                  // this lane's query point
    float4 qp = pts[i];
    ull* mybuf = &abuf[threadIdx.x * CAP];

    float md[KNN]; int mi[KNN];
#pragma unroll
    for (int k = 0; k < KNN; k++) { md[k] = 3.4e38f; mi[k] = 0; }
    float maxv = 3.4e38f; int maxp = 0; int cnt = 0;

    int cbase = wv * 1024;                       // this wave's candidate range
    float4 cc[4];
#pragma unroll
    for (int u = 0; u < 4; u++) cc[u] = pts[cbase + u];

    for (int m = 0; m < 1024; m += 4) {
        float4 cu[4];
#pragma unroll
        for (int u = 0; u < 4; u++) cu[u] = cc[u];
        int mn = (m + 4 < 1024) ? (m + 4) : 0;   // last prefetch redundant
#pragma unroll
        for (int u = 0; u < 4; u++) cc[u] = pts[cbase + mn + u];

#pragma unroll
        for (int u = 0; u < 4; u++) {
            float4 c = cu[u];
            float dx = qp.x - c.x, dy = qp.y - c.y, dz = qp.z - c.z;
            float d2 = dx * dx + dy * dy + dz * dz;   // self: exactly +0, kept
            if (d2 < maxv) {
                mybuf[cnt] = ((ull)__float_as_uint(d2) << 32)
                           | (unsigned)(cbase + m + u);
                cnt++;
            }
        }
        if (__any(cnt > CAP - 4)) {              // ensure room for next 4
            drain(mybuf, cnt, md, mi, maxv, maxp);
        }
    }
    drain(mybuf, cnt, md, mi, maxv, maxp);       // remainder

    // ---- 3-round LDS merge of the four quarter-lists into wave 0 ----------
    ull* mg = abuf;                              // 64*17*8 = 8.7 KB, aliased
    for (int r = 1; r < 4; r++) {
        __syncthreads();                         // abuf/mg free & prev round read
        if (wv == r) {
#pragma unroll
            for (int k = 0; k < KNN; k++) {
                mg[lane * KNN + k] = ((ull)__float_as_uint(md[k]) << 32)
                                   | (unsigned)mi[k];
            }
        }
        __syncthreads();
        if (wv == 0) {
#pragma unroll
            for (int k = 0; k < KNN; k++) {
                ull v = mg[lane * KNN + k];
                float d = __uint_as_float((unsigned)(v >> 32));
                int ix = (int)(v & 0xffffffffULL);
                bool ins = d < maxv;
                if (__any(ins)) insertvi(d, ix, ins, md, mi, maxv, maxp);
            }
        }
    }

    // ---- epilogue on wave 0: moments -> curv, rasig2 ----------------------
    if (wv == 0) {
        float s1x = 0, s1y = 0, s1z = 0;
        float cxx = 0, cxy = 0, cxz = 0, cyy = 0, cyz = 0, czz = 0;
#pragma unroll
        for (int k = 0; k < KNN; k++) {
            float4 c = pts[mi[k]];
            float ux = c.x - qp.x, uy = c.y - qp.y, uz = c.z - qp.z;
            s1x += ux; s1y += uy; s1z += uz;
            cxx += ux * ux; cxy += ux * uy; cxz += ux * uz;
            cyy += uy * uy; cyz += uy * uz; czz += uz * uz;
        }
        const float i16 = 1.0f / 16.0f, i15 = 1.0f / 15.0f;
        float mx = s1x * i16, my = s1y * i16, mz = s1z * i16;
        float c00 = (cxx - 16.0f * mx * mx) * i15;
        float c01 = (cxy - 16.0f * mx * my) * i15;
        float c02 = (cxz - 16.0f * mx * mz) * i15;
        float c11 = (cyy - 16.0f * my * my) * i15;
        float c12 = (cyz - 16.0f * my * mz) * i15;
        float c22 = (czz - 16.0f * mz * mz) * i15;

        float curv = curv_from_cov(c00, c01, c02, c11, c12, c22);

        float v0 = c00 > 0.0f ? c00 : 0.0f;
        float v1 = c11 > 0.0f ? c11 : 0.0f;
        float v2 = c22 > 0.0f ? c22 : 0.0f;
        float r2x = 1.0f / (0.3f * (1.0f + sqrtf(v0)) + 1e-6f);
        float r2y = 1.0f / (0.3f * (1.0f + sqrtf(v1)) + 1e-6f);
        float r2z = 1.0f / (0.3f * (1.0f + sqrtf(v2)) + 1e-6f);

        int g = b * NPTS + i;
        ws[WS_CURV + g] = curv;
        ws[WS_RAS2 + 0 * 32768 + g] = r2x;
        ws[WS_RAS2 + 1 * 32768 + g] = r2y;
        ws[WS_RAS2 + 2 * 32768 + g] = r2z;

        // wave-0 curv sum -> one atomic
        float cs = curv;
        for (int off = 32; off > 0; off >>= 1) cs += __shfl_down(cs, off);
        if (lane == 0) atomicAdd(&ws[WS_CSUM + b], cs);
    }
}

// ---------------- final embedding (finalize folded in) ---------------------
__global__ void out_kernel(const float* __restrict__ xyz,
                           const float* __restrict__ ws,
                           float* __restrict__ out) {
    __shared__ float sc[3];                      // rasig1, blend, 1-blend
    if (threadIdx.x == 0) {
        const double* st = (const double*)(ws + WS_STAT);
        double gs = 0.0;
        for (int bb = 0; bb < 8; bb++) {
            for (int dd = 0; dd < 3; dd++) {
                double s = st[bb * 6 + dd], ss = st[bb * 6 + 3 + dd];
                double var = (ss - s * s / 4096.0) / 4095.0;
                gs += sqrt(var > 0.0 ? var : 0.0);
            }
        }
        gs *= (1.0 / 24.0);
        float gf = (float)gs;
        float denom = 0.3f * (1.0f + gf) + 1e-6f;
        float blend = (float)(1.0 / (1.0 + exp(-((double)gf - 0.1) * 10.0)));
        sc[0] = (float)(1.0 / (double)denom);
        sc[1] = blend;
        sc[2] = 1.0f - blend;
    }
    __syncthreads();

    int idx = blockIdx.x * 256 + (int)threadIdx.x;
    int j = idx & 127;
    int g = idx >> 7;
    int b = g >> 12;
    int f = (j < 127) ? j : 128;                      // OUT_IDX
    int d = (f >= 86) ? 2 : ((f >= 43) ? 1 : 0);
    int t = f - d * 43;
    float fv = (float)((double)(t + 1) * (2.0 / 44.0) - 1.0);  // FEAT_VAL[t]

    float x = xyz[g * 3 + d];
    float rasig1 = sc[0];
    float blend  = sc[1];
    float blendc = sc[2];
    float cmean  = ws[WS_CSUM + b] * (1.0f / 4096.0f);
    float curv   = ws[WS_CURV + g];
    float w = 1.0f / (1.0f + __expf(-10.0f * (curv - cmean)));

    float t1 = (x - fv) * rasig1;
    float e1 = blend * __expf(-0.5f * t1 * t1) + blendc * __cosf(t1);
    float t2 = (x - fv) * ws[WS_RAS2 + (d << 15) + g];
    float e2 = __expf(-0.5f * t2 * t2);
    out[idx] = w * e1 + (1.0f - w) * e2;
}

extern "C" void kernel_launch(void* const* d_in, const int* in_sizes, int n_in,
                              void* d_out, int out_size, void* d_ws, size_t ws_size,
                              hipStream_t stream) {
    const float* xyz = (const float*)d_in[0];
    float* out = (float*)d_out;
    float* ws = (float*)d_ws;

    hipMemsetAsync(ws + WS_CSUM, 0, 8 * sizeof(float), stream);
    knn_kernel<<<512, BLKT, 0, stream>>>(xyz, ws);
    out_kernel<<<out_size / 256, 256, 0, stream>>>(xyz, ws, out);
}